// Round 8
// baseline (147.687 us; speedup 1.0000x reference)
//
#include <hip/hip_runtime.h>
#include <hip/hip_bf16.h>
#include <cstdint>

#define BATCH 4096
#define DIN   512
#define DH    256
#define DG    128
#define NH    8
#define NTOT  3328
#define S2    264    // padded bf16 (shorts) row stride for z1 LDS

typedef __bf16 bf16x8 __attribute__((ext_vector_type(8)));
typedef float  f32x4  __attribute__((ext_vector_type(4)));

__device__ __forceinline__ unsigned short f2bf(float f) {
    union { float f; uint32_t u; } v; v.f = f;
    uint32_t u = v.u;
    u += 0x7fffu + ((u >> 16) & 1u);
    return (unsigned short)(u >> 16);
}
__device__ __forceinline__ float bf2f(unsigned short s) {
    union { uint32_t u; float f; } v; v.u = ((uint32_t)s) << 16;
    return v.f;
}

__device__ __forceinline__ void async16(const unsigned short* g, unsigned short* l) {
    __builtin_amdgcn_global_load_lds(
        (const __attribute__((address_space(1))) unsigned int*)(uintptr_t)g,
        (__attribute__((address_space(3))) unsigned int*)(uintptr_t)l,
        16, 0, 0);
}

// ---------------- merged prep: cvt_x + transpose/concat weights (R5-proven) ----------------
__global__ __launch_bounds__(256) void prep_kernel(const float* __restrict__ x,
                                                   const float* __restrict__ Wh,
                                                   const float* __restrict__ Wz1,
                                                   const float* __restrict__ Wz2,
                                                   unsigned short* __restrict__ xb,
                                                   unsigned short* __restrict__ Wt) {
    __shared__ float tile[32][33];
    int bid = blockIdx.x;
    int t = threadIdx.x;
    if (bid < 2048) {
        int i = (bid * 256 + t) * 4;
        float4 v = *(const float4*)(x + i);
        ushort4 o;
        o.x = f2bf(v.x); o.y = f2bf(v.y); o.z = f2bf(v.z); o.w = f2bf(v.w);
        *(ushort4*)(xb + i) = o;
        return;
    }
    int b2 = bid - 2048;
    int n0 = (b2 % 104) * 32;
    int k0 = (b2 / 104) * 32;
    const float* W; int ldn, nl;
    if (n0 < 256)       { W = Wh;  ldn = 256;  nl = n0; }
    else if (n0 < 2304) { W = Wz1; ldn = 2048; nl = n0 - 256; }
    else                { W = Wz2; ldn = 1024; nl = n0 - 2304; }
    int tx = t & 31, ty = t >> 5;
    #pragma unroll
    for (int i = 0; i < 4; i++) {
        int kk = ty + i * 8;
        tile[kk][tx] = W[(size_t)(k0 + kk) * ldn + nl + tx];
    }
    __syncthreads();
    #pragma unroll
    for (int i = 0; i < 4; i++) {
        int nn = ty + i * 8;
        Wt[(size_t)(n0 + nn) * 512 + k0 + tx] = f2bf(tile[tx][nn]);
    }
}

// ------------- fused GEMM: Zb[4096][3328](bf16) = xb @ Wt^T -------------
// R8: mfma operands SWAPPED (D-tile transposed) so each lane holds 4
// n-consecutive outputs -> epilogue = 2 packed cvt + 1 dwordx2 store per
// (i,j) instead of 64 scalar f2bf + 64 2-byte stores per thread.
__global__ __launch_bounds__(256) void gemm_kernel(const unsigned short* __restrict__ xb,
                                                   const unsigned short* __restrict__ Wt,
                                                   unsigned short* __restrict__ Zb) {
    __shared__ unsigned short As[128 * 64];
    __shared__ unsigned short Bs[128 * 64];
    const int m0 = blockIdx.y * 128;
    const int n0 = blockIdx.x * 128;
    const int t = threadIdx.x;
    const int w = t >> 6, lane = t & 63;
    const int wm = (w >> 1) * 64, wn = (w & 1) * 64;
    const int lrow = lane & 15, q = lane >> 4;

    f32x4 acc[4][4] = {};

    for (int k0 = 0; k0 < DIN; k0 += 64) {
        __syncthreads();
        #pragma unroll
        for (int j = 0; j < 4; j++) {
            int gidx = (w * 4 + j) * 64 + lane;
            int row = gidx >> 3, slot = gidx & 7;
            int src = slot ^ (row & 7);
            const unsigned short* ga = xb + (size_t)(m0 + row) * DIN + k0 + src * 8;
            const unsigned short* gb = Wt + (size_t)(n0 + row) * DIN + k0 + src * 8;
            async16(ga, As + (w * 4 + j) * 512);
            async16(gb, Bs + (w * 4 + j) * 512);
        }
        __syncthreads();
        #pragma unroll
        for (int ks = 0; ks < 2; ks++) {
            bf16x8 af[4], bfr[4];
            #pragma unroll
            for (int i = 0; i < 4; i++) {
                int row = wm + i * 16 + lrow;
                int phys = (ks * 4 + q) ^ (row & 7);
                af[i] = *reinterpret_cast<const bf16x8*>(As + row * 64 + phys * 8);
            }
            #pragma unroll
            for (int j = 0; j < 4; j++) {
                int row = wn + j * 16 + lrow;
                int phys = (ks * 4 + q) ^ (row & 7);
                bfr[j] = *reinterpret_cast<const bf16x8*>(Bs + row * 64 + phys * 8);
            }
            // swapped operands: acc[i][j] holds D^T tile
            #pragma unroll
            for (int i = 0; i < 4; i++)
                #pragma unroll
                for (int j = 0; j < 4; j++)
                    acc[i][j] = __builtin_amdgcn_mfma_f32_16x16x32_bf16(bfr[j], af[i], acc[i][j], 0, 0, 0);
        }
    }
    // swapped C/D: lane holds m = wm+i*16+lrow (from af, now B-operand),
    //              n = wn+j*16+q*4+r (from bfr, now A-operand), r=0..3
    #pragma unroll
    for (int i = 0; i < 4; i++)
        #pragma unroll
        for (int j = 0; j < 4; j++) {
            int row = m0 + wm + i * 16 + lrow;
            int col = n0 + wn + j * 16 + q * 4;
            __hip_bfloat162 p0 = __float22bfloat162_rn(float2{acc[i][j][0], acc[i][j][1]});
            __hip_bfloat162 p1 = __float22bfloat162_rn(float2{acc[i][j][2], acc[i][j][3]});
            union { __hip_bfloat162 h[2]; uint2 u; } pk;
            pk.h[0] = p0; pk.h[1] = p1;
            *(uint2*)(Zb + (size_t)row * NTOT + col) = pk.u;
        }
}

// ------- per-batch: LN -> h ; MFMA Gram ; MFMA standardize+tanh ; y (R7-proven, FROZEN) -------
__global__ __launch_bounds__(256) void attn_kernel(const unsigned short* __restrict__ Zb,
                                                   const float* __restrict__ bh,
                                                   const float* __restrict__ lns,
                                                   const float* __restrict__ lnb,
                                                   float* __restrict__ h_out,
                                                   float* __restrict__ y_out) {
    __shared__ unsigned short z1s[16 * S2];    // bf16 [h][d]; rows 0..7 z1, row 8 ones, 9..15 uninit
    __shared__ unsigned short z2s[NH * DG];    // bf16 [h*128+g]
    __shared__ unsigned short z1cb[DH * 8];    // centered z1 bf16 [d][h]
    __shared__ unsigned short z2A[DG * 8];     // z2*A bf16 [g][h]
    __shared__ unsigned short zpad[8];         // 16B zeros
    __shared__ float hs[DH];
    __shared__ float GL[9][9];
    __shared__ float red[4][3];
    const int b = blockIdx.x;
    const int t = threadIdx.x;
    const int wv = t >> 6, lane = t & 63;
    const int lrow = lane & 15, q = lane >> 4;
    const unsigned short* Zrow = Zb + (size_t)b * NTOT;

    // ---- stage: raw bf16 copies, no conversion ----
    {
        uint4 v1 = *(const uint4*)(Zrow + 256 + t * 8);
        *(uint4*)(z1s + (t >> 5) * S2 + (t & 31) * 8) = v1;
        if (t < 128) {
            uint4 v2 = *(const uint4*)(Zrow + 2304 + t * 8);
            *(uint4*)(z2s + t * 8) = v2;
        }
        z1s[8 * S2 + t] = 0x3F80;   // bf16 1.0 (ones row)
        if (t < 8) zpad[t] = 0;
    }
    // ---- LN partials (hpre direct from global) ----
    float v = fmaxf(bf2f(Zrow[t]) + bh[t], 0.0f);
    float s = v, sq = v * v;
    #pragma unroll
    for (int m = 32; m >= 1; m >>= 1) {
        s  += __shfl_xor(s,  m, 64);
        sq += __shfl_xor(sq, m, 64);
    }
    if (lane == 0) { red[wv][0] = s; red[wv][1] = sq; }
    __syncthreads();   // (#1) staging + LN partials

    // ---- Gram via MFMA (wave 3 only; wave-uniform branch) ----
    if (wv == 3) {
        f32x4 g = {};
        #pragma unroll
        for (int ks = 0; ks < 8; ks++) {
            bf16x8 fr = *reinterpret_cast<const bf16x8*>(z1s + lrow * S2 + ks * 32 + q * 8);
            g = __builtin_amdgcn_mfma_f32_16x16x32_bf16(fr, fr, g, 0, 0, 0);
        }
        #pragma unroll
        for (int r = 0; r < 4; r++) {
            int row = q * 4 + r;
            if (row < 9 && lrow < 9) GL[row][lrow] = g[r];
        }
    }
    // ---- LN final -> h, Hsum partials ----
    {
        float ss = red[0][0] + red[1][0] + red[2][0] + red[3][0];
        float qq = red[0][1] + red[1][1] + red[2][1] + red[3][1];
        float mu  = ss * (1.0f / 256.0f);
        float var = qq * (1.0f / 256.0f) - mu * mu;
        float hval = (v - mu) * rsqrtf(var + 1e-6f) * lns[t] + lnb[t];
        hs[t] = hval;
        h_out[(size_t)b * DH + t] = hval;
        float hp = hval;
        #pragma unroll
        for (int m = 32; m >= 1; m >>= 1) hp += __shfl_xor(hp, m, 64);
        if (lane == 0) red[wv][2] = hp;
    }
    __syncthreads();   // (#2) GL + hs + Hsum partials

    // ---- repack centered z1 -> [d][h] bf16 (all threads, t = d) ----
    {
        unsigned short pk[8];
        #pragma unroll
        for (int h = 0; h < NH; h++) {
            float c = bf2f(z1s[h * S2 + t]) - GL[h][8] * (1.0f / 256.0f);
            pk[h] = f2bf(c);
        }
        ushort4 lo = {pk[0], pk[1], pk[2], pk[3]};
        ushort4 hi = {pk[4], pk[5], pk[6], pk[7]};
        *(ushort4*)(z1cb + t * 8)     = lo;
        *(ushort4*)(z1cb + t * 8 + 4) = hi;
    }
    // ---- stats + scaled-z2 bf16 fragments (t < 128, g = t) ----
    if (t < DG) {
        float z2g[NH];
        #pragma unroll
        for (int h = 0; h < NH; h++) z2g[h] = bf2f(z2s[h * DG + t]);
        float mug = 0.f, qg = 0.f;
        #pragma unroll
        for (int h = 0; h < NH; h++) {
            mug += z2g[h] * GL[h][8];
            float inn = 0.f;
            #pragma unroll
            for (int h2 = 0; h2 < NH; h2++) inn += z2g[h2] * GL[h][h2];
            qg += z2g[h] * inn;
        }
        mug *= (1.0f / 256.0f);
        qg  *= (1.0f / 256.0f);
        float vg = fmaxf(qg - mug * mug, 0.0f);
        float A = 2.0f * 1.4426950408889634f / (sqrtf(vg) + 1e-6f);
        unsigned short pk[8];
        #pragma unroll
        for (int h = 0; h < NH; h++) pk[h] = f2bf(z2g[h] * A);
        ushort4 lo = {pk[0], pk[1], pk[2], pk[3]};
        ushort4 hi = {pk[4], pk[5], pk[6], pk[7]};
        *(ushort4*)(z2A + t * 8)     = lo;
        *(ushort4*)(z2A + t * 8 + 4) = hi;
    }
    __syncthreads();   // (#3) fragments ready

    // ---- main: per wave 2 g-tiles of 16, 16 d-tiles; hv preloaded ----
    const unsigned short* bptr = (q == 0) ? (z1cb + lrow * 8) : zpad;
    const int binc = (q == 0) ? 128 : 0;
    bf16x8 af[2];
    #pragma unroll
    for (int gt = 0; gt < 2; gt++) {
        const unsigned short* aptr = (q == 0) ? (z2A + (wv * 32 + gt * 16 + lrow) * 8) : zpad;
        af[gt] = *reinterpret_cast<const bf16x8*>(aptr);
    }
    float hv[16];
    #pragma unroll
    for (int dt = 0; dt < 16; dt++) hv[dt] = hs[dt * 16 + lrow];

    f32x4 czero = {};
    float yn[2][4] = {};
    #pragma unroll 4
    for (int dt = 0; dt < 16; dt++) {
        bf16x8 bfr = *reinterpret_cast<const bf16x8*>(bptr + dt * binc);
        #pragma unroll
        for (int gt = 0; gt < 2; gt++) {
            f32x4 c = __builtin_amdgcn_mfma_f32_16x16x32_bf16(af[gt], bfr, czero, 0, 0, 0);
            #pragma unroll
            for (int r = 0; r < 4; r++) {
                float e = __builtin_amdgcn_exp2f(c[r]);
                yn[gt][r] = fmaf(hv[dt], __builtin_amdgcn_rcpf(e + 1.0f), yn[gt][r]);
            }
        }
    }
    #pragma unroll
    for (int m = 1; m <= 8; m <<= 1)
        #pragma unroll
        for (int gt = 0; gt < 2; gt++)
            #pragma unroll
            for (int r = 0; r < 4; r++)
                yn[gt][r] += __shfl_xor(yn[gt][r], m, 64);
    if (lrow == 0) {
        float Hsum = red[0][2] + red[1][2] + red[2][2] + red[3][2];
        #pragma unroll
        for (int gt = 0; gt < 2; gt++)
            #pragma unroll
            for (int r = 0; r < 4; r++)
                y_out[(size_t)b * DG + wv * 32 + gt * 16 + q * 4 + r] = Hsum - 2.0f * yn[gt][r];
    }
}

extern "C" void kernel_launch(void* const* d_in, const int* in_sizes, int n_in,
                              void* d_out, int out_size, void* d_ws, size_t ws_size,
                              hipStream_t stream) {
    const float* x   = (const float*)d_in[0];
    const float* Wh  = (const float*)d_in[1];
    const float* bh  = (const float*)d_in[2];
    const float* Wz1 = (const float*)d_in[3];
    const float* Wz2 = (const float*)d_in[4];
    const float* lns = (const float*)d_in[5];
    const float* lnb = (const float*)d_in[6];
    float* h_out = (float*)d_out;
    float* y_out = h_out + (size_t)BATCH * DH;

    char* ws = (char*)d_ws;
    unsigned short* Zb = (unsigned short*)ws;               // 27,262,976 B
    unsigned short* xb = (unsigned short*)(ws + 27262976);  //  4,194,304 B
    unsigned short* Wt = (unsigned short*)(ws + 31457280);  //  3,407,872 B (~34.9 MB)

    prep_kernel<<<3712, 256, 0, stream>>>(x, Wh, Wz1, Wz2, xb, Wt);
    gemm_kernel<<<dim3(NTOT / 128, BATCH / 128), 256, 0, stream>>>(xb, Wt, Zb);
    attn_kernel<<<BATCH, 256, 0, stream>>>(Zb, bh, lns, lnb, h_out, y_out);
}

// Round 9
// 142.339 us; speedup vs baseline: 1.0376x; 1.0376x over previous
//
#include <hip/hip_runtime.h>
#include <hip/hip_bf16.h>
#include <cstdint>

#define BATCH 4096
#define DIN   512
#define DH    256
#define DG    128
#define NH    8
#define NTOT  3328
#define RPB   8          // attn rows per block
#define SH    264        // h-slot stride in shorts (528B rows -> 2-way banks, free)
#define RREG  (9 * SH)   // per-row z1 region: 8 heads + ones row

typedef __bf16 bf16x8 __attribute__((ext_vector_type(8)));
typedef float  f32x4  __attribute__((ext_vector_type(4)));

__device__ __forceinline__ unsigned short f2bf(float f) {
    union { float f; uint32_t u; } v; v.f = f;
    uint32_t u = v.u;
    u += 0x7fffu + ((u >> 16) & 1u);
    return (unsigned short)(u >> 16);
}
__device__ __forceinline__ float bf2f(unsigned short s) {
    union { uint32_t u; float f; } v; v.u = ((uint32_t)s) << 16;
    return v.f;
}

__device__ __forceinline__ void async16(const unsigned short* g, unsigned short* l) {
    __builtin_amdgcn_global_load_lds(
        (const __attribute__((address_space(1))) unsigned int*)(uintptr_t)g,
        (__attribute__((address_space(3))) unsigned int*)(uintptr_t)l,
        16, 0, 0);
}

// ---------------- merged prep: cvt_x + transpose/concat weights (R5-proven) ----------------
__global__ __launch_bounds__(256) void prep_kernel(const float* __restrict__ x,
                                                   const float* __restrict__ Wh,
                                                   const float* __restrict__ Wz1,
                                                   const float* __restrict__ Wz2,
                                                   unsigned short* __restrict__ xb,
                                                   unsigned short* __restrict__ Wt) {
    __shared__ float tile[32][33];
    int bid = blockIdx.x;
    int t = threadIdx.x;
    if (bid < 2048) {
        int i = (bid * 256 + t) * 4;
        float4 v = *(const float4*)(x + i);
        ushort4 o;
        o.x = f2bf(v.x); o.y = f2bf(v.y); o.z = f2bf(v.z); o.w = f2bf(v.w);
        *(ushort4*)(xb + i) = o;
        return;
    }
    int b2 = bid - 2048;
    int n0 = (b2 % 104) * 32;
    int k0 = (b2 / 104) * 32;
    const float* W; int ldn, nl;
    if (n0 < 256)       { W = Wh;  ldn = 256;  nl = n0; }
    else if (n0 < 2304) { W = Wz1; ldn = 2048; nl = n0 - 256; }
    else                { W = Wz2; ldn = 1024; nl = n0 - 2304; }
    int tx = t & 31, ty = t >> 5;
    #pragma unroll
    for (int i = 0; i < 4; i++) {
        int kk = ty + i * 8;
        tile[kk][tx] = W[(size_t)(k0 + kk) * ldn + nl + tx];
    }
    __syncthreads();
    #pragma unroll
    for (int i = 0; i < 4; i++) {
        int nn = ty + i * 8;
        Wt[(size_t)(n0 + nn) * 512 + k0 + tx] = f2bf(tile[tx][nn]);
    }
}

// ------------- fused GEMM: Zb[4096][3328](bf16) = xb @ Wt^T (R7-proven) -------------
__global__ __launch_bounds__(256) void gemm_kernel(const unsigned short* __restrict__ xb,
                                                   const unsigned short* __restrict__ Wt,
                                                   unsigned short* __restrict__ Zb) {
    __shared__ unsigned short As[128 * 64];
    __shared__ unsigned short Bs[128 * 64];
    const int m0 = blockIdx.y * 128;
    const int n0 = blockIdx.x * 128;
    const int t = threadIdx.x;
    const int w = t >> 6, lane = t & 63;
    const int wm = (w >> 1) * 64, wn = (w & 1) * 64;
    const int lrow = lane & 15, q = lane >> 4;

    f32x4 acc[4][4] = {};

    for (int k0 = 0; k0 < DIN; k0 += 64) {
        __syncthreads();
        #pragma unroll
        for (int j = 0; j < 4; j++) {
            int gidx = (w * 4 + j) * 64 + lane;
            int row = gidx >> 3, slot = gidx & 7;
            int src = slot ^ (row & 7);
            const unsigned short* ga = xb + (size_t)(m0 + row) * DIN + k0 + src * 8;
            const unsigned short* gb = Wt + (size_t)(n0 + row) * DIN + k0 + src * 8;
            async16(ga, As + (w * 4 + j) * 512);
            async16(gb, Bs + (w * 4 + j) * 512);
        }
        __syncthreads();
        #pragma unroll
        for (int ks = 0; ks < 2; ks++) {
            bf16x8 af[4], bfr[4];
            #pragma unroll
            for (int i = 0; i < 4; i++) {
                int row = wm + i * 16 + lrow;
                int phys = (ks * 4 + q) ^ (row & 7);
                af[i] = *reinterpret_cast<const bf16x8*>(As + row * 64 + phys * 8);
            }
            #pragma unroll
            for (int j = 0; j < 4; j++) {
                int row = wn + j * 16 + lrow;
                int phys = (ks * 4 + q) ^ (row & 7);
                bfr[j] = *reinterpret_cast<const bf16x8*>(Bs + row * 64 + phys * 8);
            }
            #pragma unroll
            for (int i = 0; i < 4; i++)
                #pragma unroll
                for (int j = 0; j < 4; j++)
                    acc[i][j] = __builtin_amdgcn_mfma_f32_16x16x32_bf16(af[i], bfr[j], acc[i][j], 0, 0, 0);
        }
    }
    #pragma unroll
    for (int i = 0; i < 4; i++)
        #pragma unroll
        for (int j = 0; j < 4; j++) {
            int col = n0 + wn + j * 16 + lrow;
            int rbase = m0 + wm + i * 16 + q * 4;
            #pragma unroll
            for (int r = 0; r < 4; r++)
                Zb[(size_t)(rbase + r) * NTOT + col] = f2bf(acc[i][j][r]);
        }
}

// ------- 8-row attn block: LN ; Gram-MFMA ; in-place fragments ; MFMA tanh ; y -------
// R7 per-row algorithm verbatim; batching amortizes phases (4 barriers / 8 rows).
__global__ __launch_bounds__(256, 2) void attn_kernel(const unsigned short* __restrict__ Zb,
                                                      const float* __restrict__ bh,
                                                      const float* __restrict__ lns,
                                                      const float* __restrict__ lnb,
                                                      float* __restrict__ h_out,
                                                      float* __restrict__ y_out) {
    // z1a row region: raw z1 [h][d] (h=0..7, ones at 8); after repack, bytes
    // 0..4095 of the region are overwritten with z1cb [d][h] 16B rows.
    __shared__ __align__(16) unsigned short z1a[RPB * RREG + 7 * SH];  // 41,712 B
    __shared__ __align__(16) unsigned short z2b[RPB * 1024];           // raw [h][g] -> in-place z2A [g][h]
    __shared__ __align__(16) float hsr[RPB][DH];                       // 8 KB
    __shared__ float GLr[RPB][9][9];
    __shared__ float redH[RPB];
    __shared__ __align__(16) unsigned short zpad[8];
    const int b0 = blockIdx.x * RPB;
    const int t = threadIdx.x;
    const int wv = t >> 6, lane = t & 63;
    const int lrow = lane & 15, q = lane >> 4;

    // ---- stage: z1 (8 uint4/thread) + z2 raw (4 uint4/thread) + ones + zpad ----
    #pragma unroll
    for (int r = 0; r < RPB; r++) {
        const unsigned short* Zr = Zb + (size_t)(b0 + r) * NTOT;
        uint4 v = *(const uint4*)(Zr + 256 + t * 8);
        *(uint4*)(z1a + r * RREG + (t >> 5) * SH + (t & 31) * 8) = v;
        z1a[r * RREG + 8 * SH + t] = 0x3F80;   // bf16 1.0 ones row
    }
    #pragma unroll
    for (int i = 0; i < 4; i++) {
        int idx = i * 256 + t;
        int r = idx >> 7, c = idx & 127;
        uint4 v = *(const uint4*)(Zb + (size_t)(b0 + r) * NTOT + 2304 + c * 8);
        *(uint4*)(z2b + r * 1024 + c * 8) = v;
    }
    if (t < 8) zpad[t] = 0;

    // ---- LN: row = t>>5 lives in one 32-lane half -> no barrier needed ----
    {
        int r = t >> 5, d0 = (t & 31) * 8;
        const unsigned short* Zr = Zb + (size_t)(b0 + r) * NTOT;
        uint4 hp4 = *(const uint4*)(Zr + d0);
        unsigned short hu[8];
        *(uint4*)hu = hp4;
        float4 ba = *(const float4*)(bh + d0);
        float4 bb = *(const float4*)(bh + d0 + 4);
        float vv[8];
        vv[0] = fmaxf(bf2f(hu[0]) + ba.x, 0.f); vv[1] = fmaxf(bf2f(hu[1]) + ba.y, 0.f);
        vv[2] = fmaxf(bf2f(hu[2]) + ba.z, 0.f); vv[3] = fmaxf(bf2f(hu[3]) + ba.w, 0.f);
        vv[4] = fmaxf(bf2f(hu[4]) + bb.x, 0.f); vv[5] = fmaxf(bf2f(hu[5]) + bb.y, 0.f);
        vv[6] = fmaxf(bf2f(hu[6]) + bb.z, 0.f); vv[7] = fmaxf(bf2f(hu[7]) + bb.w, 0.f);
        float s = 0.f, sq = 0.f;
        #pragma unroll
        for (int i = 0; i < 8; i++) { s += vv[i]; sq += vv[i] * vv[i]; }
        #pragma unroll
        for (int m = 16; m >= 1; m >>= 1) {
            s  += __shfl_xor(s,  m, 64);
            sq += __shfl_xor(sq, m, 64);
        }
        float mu  = s * (1.0f / 256.0f);
        float var = sq * (1.0f / 256.0f) - mu * mu;
        float rs = rsqrtf(var + 1e-6f);
        float4 la = *(const float4*)(lns + d0);
        float4 lb = *(const float4*)(lns + d0 + 4);
        float4 oa = *(const float4*)(lnb + d0);
        float4 ob = *(const float4*)(lnb + d0 + 4);
        float hvv[8];
        hvv[0] = (vv[0] - mu) * rs * la.x + oa.x; hvv[1] = (vv[1] - mu) * rs * la.y + oa.y;
        hvv[2] = (vv[2] - mu) * rs * la.z + oa.z; hvv[3] = (vv[3] - mu) * rs * la.w + oa.w;
        hvv[4] = (vv[4] - mu) * rs * lb.x + ob.x; hvv[5] = (vv[5] - mu) * rs * lb.y + ob.y;
        hvv[6] = (vv[6] - mu) * rs * lb.z + ob.z; hvv[7] = (vv[7] - mu) * rs * lb.w + ob.w;
        *(float4*)(&hsr[r][d0])     = float4{hvv[0], hvv[1], hvv[2], hvv[3]};
        *(float4*)(&hsr[r][d0 + 4]) = float4{hvv[4], hvv[5], hvv[6], hvv[7]};
        float* ho = h_out + (size_t)(b0 + r) * DH + d0;
        *(float4*)ho       = float4{hvv[0], hvv[1], hvv[2], hvv[3]};
        *(float4*)(ho + 4) = float4{hvv[4], hvv[5], hvv[6], hvv[7]};
        float hp = 0.f;
        #pragma unroll
        for (int i = 0; i < 8; i++) hp += hvv[i];
        #pragma unroll
        for (int m = 16; m >= 1; m >>= 1) hp += __shfl_xor(hp, m, 64);
        if ((t & 31) == 0) redH[r] = hp;
    }
    __syncthreads();   // (#1) staging + redH visible

    // ---- Gram via MFMA: wave wv -> rows 2wv, 2wv+1 (same wave as its repack) ----
    #pragma unroll
    for (int rr = 0; rr < 2; rr++) {
        int r = wv * 2 + rr;
        f32x4 g = {};
        #pragma unroll
        for (int ks = 0; ks < 8; ks++) {
            bf16x8 fr = *reinterpret_cast<const bf16x8*>(z1a + r * RREG + lrow * SH + ks * 32 + q * 8);
            g = __builtin_amdgcn_mfma_f32_16x16x32_bf16(fr, fr, g, 0, 0, 0);
        }
        #pragma unroll
        for (int i = 0; i < 4; i++) {
            int crow = q * 4 + i;
            if (crow < 9 && lrow < 9) GLr[r][crow][lrow] = g[i];
        }
    }
    // ---- repack reads (centered z1 -> regs); row = t>>5 matches this wave's Gram rows ----
    uint32_t pr[8][4];
    {
        int r = t >> 5, la = t & 31;
        float mh[8];
        #pragma unroll
        for (int h = 0; h < NH; h++) mh[h] = GLr[r][h][8] * (1.0f / 256.0f);
        #pragma unroll
        for (int jj = 0; jj < 8; jj++) {
            int d = la + 32 * jj;
            #pragma unroll
            for (int h2 = 0; h2 < 4; h2++) {
                float c0 = bf2f(z1a[r * RREG + (2 * h2) * SH + d])     - mh[2 * h2];
                float c1 = bf2f(z1a[r * RREG + (2 * h2 + 1) * SH + d]) - mh[2 * h2 + 1];
                pr[jj][h2] = (uint32_t)f2bf(c0) | ((uint32_t)f2bf(c1) << 16);
            }
        }
    }
    __syncthreads();   // (#2) all raw-z1 reads done; GLr visible to all

    // ---- write z1cb in place; stats reads (raw z2 + GL) -> regs ----
    {
        int r = t >> 5, la = t & 31;
        #pragma unroll
        for (int jj = 0; jj < 8; jj++) {
            int d = la + 32 * jj;
            *(uint4*)(z1a + r * RREG + d * 8) = uint4{pr[jj][0], pr[jj][1], pr[jj][2], pr[jj][3]};
        }
    }
    uint32_t ps[4][4];
    #pragma unroll
    for (int i = 0; i < 4; i++) {
        int idx = i * 256 + t;
        int r = idx >> 7, g = idx & 127;
        float z2g[NH];
        #pragma unroll
        for (int h = 0; h < NH; h++) z2g[h] = bf2f(z2b[r * 1024 + h * 128 + g]);
        float mug = 0.f, qg = 0.f;
        #pragma unroll
        for (int h = 0; h < NH; h++) {
            mug += z2g[h] * GLr[r][h][8];
            float inn = 0.f;
            #pragma unroll
            for (int h2 = 0; h2 < NH; h2++) inn += z2g[h2] * GLr[r][h][h2];
            qg += z2g[h] * inn;
        }
        mug *= (1.0f / 256.0f);
        qg  *= (1.0f / 256.0f);
        float vg = fmaxf(qg - mug * mug, 0.0f);
        float A = 2.0f * 1.4426950408889634f / (sqrtf(vg) + 1e-6f);
        #pragma unroll
        for (int h2 = 0; h2 < 4; h2++)
            ps[i][h2] = (uint32_t)f2bf(z2g[2 * h2] * A) | ((uint32_t)f2bf(z2g[2 * h2 + 1] * A) << 16);
    }
    __syncthreads();   // (#3) raw-z2 reads done; z1cb written

    // ---- write z2A in place ----
    #pragma unroll
    for (int i = 0; i < 4; i++) {
        int idx = i * 256 + t;
        int r = idx >> 7, g = idx & 127;
        *(uint4*)(z2b + r * 1024 + g * 8) = uint4{ps[i][0], ps[i][1], ps[i][2], ps[i][3]};
    }
    __syncthreads();   // (#4) fragments ready

    // ---- main: wave wv -> rows 2wv, 2wv+1; 8 g-tiles x 16 d-tiles per row ----
    const int ra = wv * 2, rb = wv * 2 + 1;
    const unsigned short* bpA = (q == 0) ? (z1a + ra * RREG + lrow * 8) : zpad;
    const unsigned short* bpB = (q == 0) ? (z1a + rb * RREG + lrow * 8) : zpad;
    const int binc = (q == 0) ? 128 : 0;
    bf16x8 afA[8], afB[8];
    #pragma unroll
    for (int gt = 0; gt < 8; gt++) {
        const unsigned short* pa = (q == 0) ? (z2b + ra * 1024 + (gt * 16 + lrow) * 8) : zpad;
        const unsigned short* pb = (q == 0) ? (z2b + rb * 1024 + (gt * 16 + lrow) * 8) : zpad;
        afA[gt] = *reinterpret_cast<const bf16x8*>(pa);
        afB[gt] = *reinterpret_cast<const bf16x8*>(pb);
    }
    f32x4 czero = {};
    float ynA[8][4] = {}, ynB[8][4] = {};
    #pragma unroll 2
    for (int dt = 0; dt < 16; dt++) {
        bf16x8 bA = *reinterpret_cast<const bf16x8*>(bpA + dt * binc);
        bf16x8 bB = *reinterpret_cast<const bf16x8*>(bpB + dt * binc);
        float hvA = hsr[ra][dt * 16 + lrow];
        float hvB = hsr[rb][dt * 16 + lrow];
        #pragma unroll
        for (int gt = 0; gt < 8; gt++) {
            f32x4 cA = __builtin_amdgcn_mfma_f32_16x16x32_bf16(afA[gt], bA, czero, 0, 0, 0);
            f32x4 cB = __builtin_amdgcn_mfma_f32_16x16x32_bf16(afB[gt], bB, czero, 0, 0, 0);
            #pragma unroll
            for (int r4 = 0; r4 < 4; r4++) {
                float eA = __builtin_amdgcn_exp2f(cA[r4]);
                ynA[gt][r4] = fmaf(hvA, __builtin_amdgcn_rcpf(eA + 1.0f), ynA[gt][r4]);
                float eB = __builtin_amdgcn_exp2f(cB[r4]);
                ynB[gt][r4] = fmaf(hvB, __builtin_amdgcn_rcpf(eB + 1.0f), ynB[gt][r4]);
            }
        }
    }
    #pragma unroll
    for (int m = 1; m <= 8; m <<= 1)
        #pragma unroll
        for (int gt = 0; gt < 8; gt++)
            #pragma unroll
            for (int r4 = 0; r4 < 4; r4++) {
                ynA[gt][r4] += __shfl_xor(ynA[gt][r4], m, 64);
                ynB[gt][r4] += __shfl_xor(ynB[gt][r4], m, 64);
            }
    if (lrow == 0) {
        float HsA = redH[ra], HsB = redH[rb];
        #pragma unroll
        for (int gt = 0; gt < 8; gt++)
            #pragma unroll
            for (int r4 = 0; r4 < 4; r4++) {
                y_out[(size_t)(b0 + ra) * DG + gt * 16 + q * 4 + r4] = HsA - 2.0f * ynA[gt][r4];
                y_out[(size_t)(b0 + rb) * DG + gt * 16 + q * 4 + r4] = HsB - 2.0f * ynB[gt][r4];
            }
    }
}

extern "C" void kernel_launch(void* const* d_in, const int* in_sizes, int n_in,
                              void* d_out, int out_size, void* d_ws, size_t ws_size,
                              hipStream_t stream) {
    const float* x   = (const float*)d_in[0];
    const float* Wh  = (const float*)d_in[1];
    const float* bh  = (const float*)d_in[2];
    const float* Wz1 = (const float*)d_in[3];
    const float* Wz2 = (const float*)d_in[4];
    const float* lns = (const float*)d_in[5];
    const float* lnb = (const float*)d_in[6];
    float* h_out = (float*)d_out;
    float* y_out = h_out + (size_t)BATCH * DH;

    char* ws = (char*)d_ws;
    unsigned short* Zb = (unsigned short*)ws;               // 27,262,976 B
    unsigned short* xb = (unsigned short*)(ws + 27262976);  //  4,194,304 B
    unsigned short* Wt = (unsigned short*)(ws + 31457280);  //  3,407,872 B (~34.9 MB)

    prep_kernel<<<3712, 256, 0, stream>>>(x, Wh, Wz1, Wz2, xb, Wt);
    gemm_kernel<<<dim3(NTOT / 128, BATCH / 128), 256, 0, stream>>>(xb, Wt, Zb);
    attn_kernel<<<BATCH / RPB, 256, 0, stream>>>(Zb, bh, lns, lnb, h_out, y_out);
}